// Round 7
// baseline (259.321 us; speedup 1.0000x reference)
//
#include <hip/hip_runtime.h>
#include <math.h>

// GoBERT: GATConv(4x32) -> BN -> GCNConv(128) -> BN -> GlobalAttention -> FC
// Round 13: revert R12's readlane gather (3rd failed gather restructure:
// R8 neutral, R11 -32us, R12 -9.5us) -> aggr kernels restored to the proven
// R10 code (LDS-staged indices, readfirstlane, triple-buffer, lb(512,2)).
// New wins this round, away from the gather loop:
//  - k_prep weight transpose split across 16 blocks (was 2 serial stragglers
//    of ~20us gating binA->binB; each block re-stages W into LDS, trivial).
//  - GlobalAttention pooling fused into k_gcn_aggr: per-block LDS combine
//    (batch-sorted nodes -> ~1 graph/block -> ~1 atomic pair/block) into
//    se/sf[64]; k_pool replaced by trivial k_fin<<<1,64>>>.
// prep-binA/gemm/binB unchanged from R10.

#define NEG_SLOPE 0.2f
#define BKT_BITS 7
#define BKT_SIZE 128
#define CHUNK_A 2048
#define BCAP 4096
#define WPB 16          // weight-prep blocks in k_prep

typedef __attribute__((ext_vector_type(8))) short short8v;
typedef __attribute__((ext_vector_type(4))) float floatx4;

__device__ __forceinline__ unsigned pack_bf16(float lo, float hi) {
    unsigned ua = __float_as_uint(lo);
    unsigned ub = __float_as_uint(hi);
    ua = ua + 0x7fffu + ((ua >> 16) & 1u);
    ub = ub + 0x7fffu + ((ub >> 16) & 1u);
    return (ua >> 16) | (ub & 0xffff0000u);
}

__device__ __forceinline__ unsigned short bf16_1(float v) {
    unsigned u = __float_as_uint(v);
    u = u + 0x7fffu + ((u >> 16) & 1u);
    return (unsigned short)(u >> 16);
}

// ---------------- prep: weight transpose (blocks 0..15) || binA (rest) -----
// Wt1[144][128]: rows 0-127 = W_gat^T; 128-131 = W@att_src; 132-135 =
// W@att_dst; 136-143 = 0.  Wt2[128][128] = W_gcn^T.
// Blocks 0..7: Wt1 rows 18b..18b+18. Blocks 8..15: Wt2 rows 16(b-8)..+16.
__global__ __launch_bounds__(256) void k_prep(
    const float* __restrict__ W1, const float* __restrict__ atts,
    const float* __restrict__ attd, const float* __restrict__ W2,
    unsigned short* __restrict__ Wt1, unsigned short* __restrict__ Wt2,
    const int* __restrict__ ei, int* __restrict__ bcur,
    int2* __restrict__ pairs, int E, int NB)
{
    __shared__ float sW[128 * 129];          // 64.5KB; aliased by binA branch
    const int b = blockIdx.x;
    const int tid = threadIdx.x;
    if (b < WPB) {
        const bool first = b < 8;
        const float* W = first ? W1 : W2;
        unsigned short* Wt = first ? Wt1 : Wt2;
        for (int t = tid; t < 128 * 128; t += 256)
            sW[(t >> 7) * 129 + (t & 127)] = W[t];   // coalesced global read
        __syncthreads();
        const int j0 = first ? (b * 18) : ((b - 8) * 16);
        const int jn = first ? 18 : 16;
        for (int q = tid; q < jn * 128; q += 256) {
            int j = j0 + (q >> 7), i = q & 127;
            float v;
            if (j < 128) v = sW[i * 129 + j];        // lanes vary i: no conflict
            else if (j < 132) {
                int h = j - 128; float s = 0.f;
                for (int c = 0; c < 32; c++) s += sW[i * 129 + h * 32 + c] * atts[h * 32 + c];
                v = s;
            } else if (j < 136) {
                int h = j - 132; float s = 0.f;
                for (int c = 0; c < 32; c++) s += sW[i * 129 + h * 32 + c] * attd[h * 32 + c];
                v = s;
            } else v = 0.f;
            Wt[j * 128 + i] = bf16_1(v);
        }
    } else {
        int* h    = (int*)sW;                // [512]
        int* base = h + 512;                 // [512]
        for (int i = tid; i < NB + 1; i += 256) h[i] = 0;
        __syncthreads();
        const int c0 = (b - WPB) * CHUNK_A;
        int s[8], d[8], bk[8];
#pragma unroll
        for (int k = 0; k < 8; k++) {
            int e = c0 + k * 256 + tid;
            bool v = e < E;
            s[k] = v ? ei[e] : 0;
            d[k] = v ? ei[E + e] : 0;
            bk[k] = v ? (d[k] >> BKT_BITS) : NB;
            atomicAdd(&h[bk[k]], 1);
        }
        __syncthreads();
        for (int i = tid; i < NB + 1; i += 256) {
            int c = h[i];
            base[i] = c ? atomicAdd(&bcur[i], c) : 0;
            h[i] = 0;
        }
        __syncthreads();
#pragma unroll
        for (int k = 0; k < 8; k++) {
            int r = atomicAdd(&h[bk[k]], 1);
            pairs[(size_t)bk[k] * BCAP + base[bk[k]] + r] = make_int2(s[k], d[k]);
        }
    }
}

// ---------------- MFMA GEMM: 128 rows/block, Cb[N,64 pairs] ----------------
// MODE 0 launch also hosts binB in blocks >= gemmBlocks (independent work).
template<int MODE>
__global__ __launch_bounds__(256) void k_gemm_mfma(
    const void* __restrict__ Ain, const unsigned short* __restrict__ Wt,
    unsigned* __restrict__ Cb, int N,
    const float* __restrict__ pb, const float* __restrict__ pw,
    const float* __restrict__ pb2, const float* __restrict__ dinv,
    float* __restrict__ aS, float* __restrict__ aD,
    const int2* __restrict__ pairs, const int* __restrict__ bcnt,
    int* __restrict__ csr, int* __restrict__ offs, int* __restrict__ deg,
    float* __restrict__ dinvw, int gemmBlocks)
{
    constexpr int NCT = (MODE == 0) ? 9 : 8;
    __shared__ unsigned short sA[128 * 136];
    __shared__ unsigned short sB[NCT * 16 * 136];
    const int tid = threadIdx.x;

    if (MODE == 0 && (int)blockIdx.x >= gemmBlocks) {
        // ---------------- binB: bucket -> padded CSR ----------------
        __shared__ int wtot;
        int* hist  = (int*)sA;               // [128]
        int* start = hist + 128;             // [128]
        int* cur   = start + 128;            // [128]
        const int b = blockIdx.x - gemmBlocks;
        const int lane = tid & 63;
        const int d0 = b << BKT_BITS;
        const size_t pbg = (size_t)b * BCAP;
        const int cntb = bcnt[b];
        if (tid < BKT_SIZE) { hist[tid] = 0; cur[tid] = 0; }
        __syncthreads();
        for (int i = tid; i < cntb; i += 256)
            atomicAdd(&hist[pairs[pbg + i].y - d0], 1);
        __syncthreads();
        int own = (tid < BKT_SIZE) ? hist[tid] : 0;
        int incl = own;
#pragma unroll
        for (int st = 1; st < 64; st <<= 1) {
            int t = __shfl_up(incl, st);
            if (lane >= st) incl += t;
        }
        if (tid == 63) wtot = incl;          // wave-0 total
        __syncthreads();
        if (tid < BKT_SIZE) {
            if (tid >= 64) incl += wtot;
            int abs0 = (int)pbg + (incl - own);
            start[tid] = abs0;
            int dd = d0 + tid;
            if (dd < N) {
                offs[dd] = abs0;
                deg[dd] = own;
                dinvw[dd] = rsqrtf((float)(own + 1));
            }
        }
        __syncthreads();
        for (int i = tid; i < cntb; i += 256) {
            int2 p = pairs[pbg + i];
            int ld = p.y - d0;
            int r = atomicAdd(&cur[ld], 1);
            csr[start[ld] + r] = p.x;
        }
        return;
    }

    const int n0 = blockIdx.x * 128;

    // stage B (coalesced uint4, LDS row stride 136)
    {
        const uint4* Wg = (const uint4*)Wt;
        const int nq = NCT * 16 * 16;
        for (int q = tid; q < nq; q += 256) {
            uint4 v = Wg[q];
            int j = q >> 4, seg = q & 15;
            *(uint4*)(sB + j * 136 + seg * 8) = v;
        }
    }
    // stage A
    if (MODE == 0) {
        const float* A = (const float*)Ain;
        const int w4 = tid & 31;          // float4 within row
        const int r0 = tid >> 5;          // 0..7
#pragma unroll
        for (int i = 0; i < 16; i++) {
            int r = r0 + 8 * i;
            int gn = n0 + r;
            unsigned p0 = 0, p1 = 0;
            if (gn < N) {
                float4 v = *(const float4*)(A + (size_t)gn * 128 + w4 * 4);
                p0 = pack_bf16(v.x, v.y);
                p1 = pack_bf16(v.z, v.w);
            }
            *(uint2*)(sA + r * 136 + w4 * 4) = make_uint2(p0, p1);
        }
    } else {
        const unsigned short* A = (const unsigned short*)Ain;
        const int w8 = tid & 15;          // 8-channel group within row
        const int r0 = tid >> 4;          // 0..15
        const int k0 = w8 * 8;
        float pbv[8], pwv[8], p2v[8];
        *(float4*)(pbv)     = *(const float4*)(pb + k0);
        *(float4*)(pbv + 4) = *(const float4*)(pb + k0 + 4);
        *(float4*)(pwv)     = *(const float4*)(pw + k0);
        *(float4*)(pwv + 4) = *(const float4*)(pw + k0 + 4);
        *(float4*)(p2v)     = *(const float4*)(pb2 + k0);
        *(float4*)(p2v + 4) = *(const float4*)(pb2 + k0 + 4);
#pragma unroll
        for (int i = 0; i < 8; i++) {
            int r = r0 + 16 * i;
            int gn = n0 + r;
            uint4 outv = make_uint4(0, 0, 0, 0);
            if (gn < N) {
                uint4 v = *(const uint4*)(A + (size_t)gn * 128 + k0);
                unsigned uu[4] = {v.x, v.y, v.z, v.w};
                unsigned ro[4];
#pragma unroll
                for (int q2 = 0; q2 < 4; q2++) {
                    float lo = __uint_as_float(uu[q2] << 16);
                    float hi = __uint_as_float(uu[q2] & 0xffff0000u);
                    float t;
                    t = lo + pbv[2 * q2];     t = (t > 0.f) ? t : expm1f(t); lo = t * pwv[2 * q2]     + p2v[2 * q2];
                    t = hi + pbv[2 * q2 + 1]; t = (t > 0.f) ? t : expm1f(t); hi = t * pwv[2 * q2 + 1] + p2v[2 * q2 + 1];
                    ro[q2] = pack_bf16(lo, hi);
                }
                outv = make_uint4(ro[0], ro[1], ro[2], ro[3]);
            }
            *(uint4*)(sA + r * 136 + k0) = outv;
        }
    }
    __syncthreads();

    const int wid = tid >> 6, lane = tid & 63;
    const int quad = lane >> 4, l16 = lane & 15;

    floatx4 acc[2][NCT];
#pragma unroll
    for (int rt = 0; rt < 2; rt++)
#pragma unroll
        for (int ct = 0; ct < NCT; ct++) acc[rt][ct] = (floatx4){0.f, 0.f, 0.f, 0.f};

    const unsigned short* pa0 = sA + (wid * 32 + l16) * 136 + quad * 8;
    const unsigned short* pbt = sB + l16 * 136 + quad * 8;
#pragma unroll
    for (int ks = 0; ks < 4; ks++) {
        short8v a0 = *(const short8v*)(pa0 + ks * 32);
        short8v a1 = *(const short8v*)(pa0 + 16 * 136 + ks * 32);
#pragma unroll
        for (int ct = 0; ct < NCT; ct++) {
            short8v bv = *(const short8v*)(pbt + ct * (16 * 136) + ks * 32);
            acc[0][ct] = __builtin_amdgcn_mfma_f32_16x16x32_bf16(a0, bv, acc[0][ct], 0, 0, 0);
            acc[1][ct] = __builtin_amdgcn_mfma_f32_16x16x32_bf16(a1, bv, acc[1][ct], 0, 0, 0);
        }
    }

    // epilogue: lane = rows quad*4+r, col ct*16+l16
#pragma unroll
    for (int rt = 0; rt < 2; rt++) {
#pragma unroll
        for (int r = 0; r < 4; r++) {
            int n = n0 + wid * 32 + rt * 16 + quad * 4 + r;
            if (n >= N) continue;
            float s = MODE ? dinv[n] : 1.f;
#pragma unroll
            for (int ct = 0; ct < 4; ct++) {
                Cb[(size_t)n * 64 + ct * 16 + l16] =
                    pack_bf16(acc[rt][ct][r] * s, acc[rt][ct + 4][r] * s);
            }
            if (MODE == 0) {
                float e = acc[rt][8][r];
                if (l16 < 4) aS[(size_t)n * 4 + l16] = e;
                else if (l16 < 8) aD[(size_t)n * 4 + (l16 - 4)] = e;
            }
        }
    }
}

// ---------------- GAT aggregation: 8 nodes / 512-thread block --------------
// R10-proven structure: LDS-staged indices, readfirstlane SGPR bases,
// register triple-buffer (24 gathers in flight), lb(512,2). Pads: src=n, u=0.
__global__ __launch_bounds__(512, 2) void k_gat_aggr(
    const unsigned* __restrict__ hb, const float* __restrict__ aSg,
    const float* __restrict__ aDg, const int* __restrict__ offs,
    const int* __restrict__ deg, const int* __restrict__ csr,
    unsigned short* __restrict__ raw1b, int N)
{
    __shared__ __align__(16) float s_u[8][2][64][2];
    __shared__ __align__(16) int s_s[8][64];

    const int wid = threadIdx.x >> 6;
    const int lane = threadIdx.x & 63;
    const int n = blockIdx.x * 8 + wid;
    if (n >= N) return;

    const int beg = offs[n];
    const int cnt = deg[n] + 1;                     // + self loop
    const float4 ad = *(const float4*)(aDg + (size_t)n * 4);
    const int hA = lane >> 5;
    const float* pu = &s_u[wid][hA][0][0];
    const int* ps = &s_s[wid][0];
    const unsigned* hbl = hb + lane;

    float t0 = 0.f, t1 = 0.f, t2 = 0.f, t3 = 0.f;
    float accLo = 0.f, accHi = 0.f;

    auto issue8 = [&](int j, unsigned (&v)[8]) {
        int4 A = *(const int4*)&ps[j];
        int4 B = *(const int4*)&ps[j + 4];
        int s0 = __builtin_amdgcn_readfirstlane(A.x);
        int s1 = __builtin_amdgcn_readfirstlane(A.y);
        int s2 = __builtin_amdgcn_readfirstlane(A.z);
        int s3 = __builtin_amdgcn_readfirstlane(A.w);
        int s4 = __builtin_amdgcn_readfirstlane(B.x);
        int s5 = __builtin_amdgcn_readfirstlane(B.y);
        int s6 = __builtin_amdgcn_readfirstlane(B.z);
        int s7 = __builtin_amdgcn_readfirstlane(B.w);
        v[0] = hbl[(size_t)s0 << 6];
        v[1] = hbl[(size_t)s1 << 6];
        v[2] = hbl[(size_t)s2 << 6];
        v[3] = hbl[(size_t)s3 << 6];
        v[4] = hbl[(size_t)s4 << 6];
        v[5] = hbl[(size_t)s5 << 6];
        v[6] = hbl[(size_t)s6 << 6];
        v[7] = hbl[(size_t)s7 << 6];
    };
    auto consume8 = [&](int j, unsigned (&v)[8]) {
        float4 u01 = *(const float4*)&pu[2 * j];
        float4 u23 = *(const float4*)&pu[2 * j + 4];
        float4 u45 = *(const float4*)&pu[2 * j + 8];
        float4 u67 = *(const float4*)&pu[2 * j + 12];
        float uw[16] = {u01.x, u01.y, u01.z, u01.w,
                        u23.x, u23.y, u23.z, u23.w,
                        u45.x, u45.y, u45.z, u45.w,
                        u67.x, u67.y, u67.z, u67.w};
#pragma unroll
        for (int k = 0; k < 8; k++) {
            float lo = __uint_as_float(v[k] << 16);
            float hi = __uint_as_float(v[k] & 0xffff0000u);
            accLo += uw[2 * k] * lo;
            accHi += uw[2 * k + 1] * hi;
        }
    };

    for (int base = 0; base < cnt; base += 64) {
        int idx = base + lane;
        bool valid = idx < cnt;
        int src = n;
        if (valid && idx > 0) src = csr[beg + idx - 1];
        float u0 = 0.f, u1 = 0.f, u2 = 0.f, u3 = 0.f;
        if (valid) {
            float4 as = *(const float4*)(aSg + (size_t)src * 4);
            float l0 = as.x + ad.x; l0 = (l0 > 0.f) ? l0 : NEG_SLOPE * l0;
            float l1 = as.y + ad.y; l1 = (l1 > 0.f) ? l1 : NEG_SLOPE * l1;
            float l2 = as.z + ad.z; l2 = (l2 > 0.f) ? l2 : NEG_SLOPE * l2;
            float l3 = as.w + ad.w; l3 = (l3 > 0.f) ? l3 : NEG_SLOPE * l3;
            u0 = __expf(l0); u1 = __expf(l1); u2 = __expf(l2); u3 = __expf(l3);
        }
        t0 += u0; t1 += u1; t2 += u2; t3 += u3;
        s_s[wid][lane] = src;
        *(float2*)&s_u[wid][0][lane][0] = make_float2(u0, u2);
        *(float2*)&s_u[wid][1][lane][0] = make_float2(u1, u3);

        int cc = min(64, cnt - base);
        int ccp = (cc + 7) & ~7;                    // pads contribute u=0
        int ng = ccp >> 3;
        unsigned v0[8], v1[8], v2[8];
        if (ng > 0) issue8(0, v0);
        if (ng > 1) issue8(8, v1);
        if (ng > 2) issue8(16, v2);
        if (ng > 0) consume8(0, v0);
        if (ng > 1) consume8(8, v1);
        if (ng > 2) consume8(16, v2);
        for (int j = 24; j < ccp; j += 8) {         // rare (deg > 23)
            issue8(j, v0);
            consume8(j, v0);
        }
    }
#pragma unroll
    for (int msk = 1; msk < 64; msk <<= 1) {
        t0 += __shfl_xor(t0, msk);
        t1 += __shfl_xor(t1, msk);
        t2 += __shfl_xor(t2, msk);
        t3 += __shfl_xor(t3, msk);
    }
    float sLo = (hA ? t1 : t0) + 1e-16f;
    float sHi = (hA ? t3 : t2) + 1e-16f;
    raw1b[(size_t)n * 128 + lane]      = bf16_1(accLo / sLo);
    raw1b[(size_t)n * 128 + 64 + lane] = bf16_1(accHi / sHi);
}

// ---------------- GCN aggregation + BN2/ELU/gate/fc + fused pooling --------
// R10 gather structure. Epilogue: per-wave (e, e*f) -> per-block LDS combine
// (batch-sorted nodes: ~1 graph/block) -> atomicAdd into se/sf[64].
__global__ __launch_bounds__(512, 2) void k_gcn_aggr(
    const unsigned* __restrict__ h2b, const int* __restrict__ offs,
    const int* __restrict__ deg, const int* __restrict__ csr,
    const float* __restrict__ dinv, const float* __restrict__ bgcn,
    const float* __restrict__ bn2w, const float* __restrict__ bn2b,
    const float* __restrict__ wgate, const float* __restrict__ bgate,
    const float* __restrict__ wfc, const int* __restrict__ batch,
    float* __restrict__ se, float* __restrict__ sf, int N)
{
    __shared__ __align__(16) int s_s[8][64];
    __shared__ __align__(16) float s_w[8][64];
    __shared__ int s_pg[8];
    __shared__ float s_pe[8], s_pf[8];

    const int wid = threadIdx.x >> 6;
    const int lane = threadIdx.x & 63;
    const int n = blockIdx.x * 8 + wid;
    const bool act = n < N;

    float g = 0.f, f = 0.f;
    if (act) {
        const int beg = offs[n];
        const int cnt = deg[n] + 1;
        const float dn = dinv[n];
        const int* ps = &s_s[wid][0];
        const float* pw = &s_w[wid][0];
        const unsigned* h2l = h2b + lane;

        float accLo = 0.f, accHi = 0.f;

        auto issue8 = [&](int j, unsigned (&v)[8]) {
            int4 A = *(const int4*)&ps[j];
            int4 B = *(const int4*)&ps[j + 4];
            int s0 = __builtin_amdgcn_readfirstlane(A.x);
            int s1 = __builtin_amdgcn_readfirstlane(A.y);
            int s2 = __builtin_amdgcn_readfirstlane(A.z);
            int s3 = __builtin_amdgcn_readfirstlane(A.w);
            int s4 = __builtin_amdgcn_readfirstlane(B.x);
            int s5 = __builtin_amdgcn_readfirstlane(B.y);
            int s6 = __builtin_amdgcn_readfirstlane(B.z);
            int s7 = __builtin_amdgcn_readfirstlane(B.w);
            v[0] = h2l[(size_t)s0 << 6];
            v[1] = h2l[(size_t)s1 << 6];
            v[2] = h2l[(size_t)s2 << 6];
            v[3] = h2l[(size_t)s3 << 6];
            v[4] = h2l[(size_t)s4 << 6];
            v[5] = h2l[(size_t)s5 << 6];
            v[6] = h2l[(size_t)s6 << 6];
            v[7] = h2l[(size_t)s7 << 6];
        };
        auto consume8 = [&](int j, unsigned (&v)[8]) {
            float4 wA = *(const float4*)&pw[j];
            float4 wB = *(const float4*)&pw[j + 4];
            float w8[8] = {wA.x, wA.y, wA.z, wA.w, wB.x, wB.y, wB.z, wB.w};
#pragma unroll
            for (int k = 0; k < 8; k++) {
                float lo = __uint_as_float(v[k] << 16);
                float hi = __uint_as_float(v[k] & 0xffff0000u);
                accLo += w8[k] * lo;
                accHi += w8[k] * hi;
            }
        };

        for (int base = 0; base < cnt; base += 64) {
            int idx = base + lane;
            bool valid = idx < cnt;
            int src = n;
            if (valid && idx > 0) src = csr[beg + idx - 1];
            s_s[wid][lane] = src;
            s_w[wid][lane] = valid ? 1.f : 0.f;

            int cc = min(64, cnt - base);
            int ccp = (cc + 7) & ~7;                // pads carry w=0
            int ng = ccp >> 3;
            unsigned v0[8], v1[8], v2[8];
            if (ng > 0) issue8(0, v0);
            if (ng > 1) issue8(8, v1);
            if (ng > 2) issue8(16, v2);
            if (ng > 0) consume8(0, v0);
            if (ng > 1) consume8(8, v1);
            if (ng > 2) consume8(16, v2);
            for (int j = 24; j < ccp; j += 8) {
                issue8(j, v0);
                consume8(j, v0);
            }
        }
        float v0f = dn * accLo + bgcn[lane];
        v0f = (v0f > 0.f) ? v0f : expm1f(v0f);
        v0f = v0f * bn2w[lane] + bn2b[lane];
        float v1f = dn * accHi + bgcn[lane + 64];
        v1f = (v1f > 0.f) ? v1f : expm1f(v1f);
        v1f = v1f * bn2w[lane + 64] + bn2b[lane + 64];

        g = v0f * wgate[lane] + v1f * wgate[lane + 64];
        f = v0f * wfc[lane]   + v1f * wfc[lane + 64];
#pragma unroll
        for (int msk = 1; msk < 64; msk <<= 1) {
            g += __shfl_xor(g, msk);
            f += __shfl_xor(f, msk);
        }
    }
    // ---- fused pooling: per-block combine, then se/sf atomics ----
    if (lane == 0) {
        int gid = 0; float e = 0.f, ef = 0.f;
        if (act) {
            gid = batch[n];
            e = __expf(g + bgate[0]);
            ef = e * f;
        }
        s_pg[wid] = gid; s_pe[wid] = e; s_pf[wid] = ef;
    }
    __syncthreads();
    if (threadIdx.x == 0) {
        int cg = s_pg[0]; float ce = s_pe[0], cf = s_pf[0];
        for (int i = 1; i < 8; i++) {
            if (s_pg[i] == cg) { ce += s_pe[i]; cf += s_pf[i]; }
            else {
                if (ce != 0.f) { atomicAdd(&se[cg], ce); atomicAdd(&sf[cg], cf); }
                cg = s_pg[i]; ce = s_pe[i]; cf = s_pf[i];
            }
        }
        if (ce != 0.f) { atomicAdd(&se[cg], ce); atomicAdd(&sf[cg], cf); }
    }
}

// ---------------- final: out[g] = sf/se + bfc ------------------------------
__global__ __launch_bounds__(64) void k_fin(
    const float* __restrict__ se, const float* __restrict__ sf,
    const float* __restrict__ bfc, float* __restrict__ out)
{
    int g = threadIdx.x;
    out[g] = sf[g] / (se[g] + 1e-16f) + bfc[0];
}

// ---------------------------------------------------------------------------
extern "C" void kernel_launch(void* const* d_in, const int* in_sizes, int n_in,
                              void* d_out, int out_size, void* d_ws, size_t ws_size,
                              hipStream_t stream) {
    const float* x     = (const float*)d_in[0];
    const int*   ei    = (const int*)d_in[1];
    const int*   batch = (const int*)d_in[2];
    const float* Wgat  = (const float*)d_in[3];
    const float* atts  = (const float*)d_in[4];
    const float* attd  = (const float*)d_in[5];
    const float* bgat  = (const float*)d_in[6];
    const float* bn1w  = (const float*)d_in[7];
    const float* bn1b  = (const float*)d_in[8];
    const float* Wgcn  = (const float*)d_in[9];
    const float* bgcn  = (const float*)d_in[10];
    const float* bn2w  = (const float*)d_in[11];
    const float* bn2b  = (const float*)d_in[12];
    const float* wgate = (const float*)d_in[13];
    const float* bgate = (const float*)d_in[14];
    const float* wfc   = (const float*)d_in[15];
    const float* bfc   = (const float*)d_in[16];
    float* out = (float*)d_out;

    const int N = in_sizes[0] / 128;
    const int E = in_sizes[1] / 2;
    const int NB = (N + BKT_SIZE - 1) / BKT_SIZE;
    const int NBA = (E + CHUNK_A - 1) / CHUNK_A;   // binA blocks

    unsigned* hb  = (unsigned*)d_ws;               // bf16 h table   [N*64]
    unsigned* h2b = hb + (size_t)N * 64;           // bf16 h2s table [N*64]
    unsigned short* raw1b = (unsigned short*)(h2b + (size_t)N * 64); // [N*128]
    float* aS    = (float*)(raw1b + (size_t)N * 128); // [N*4]
    float* aD    = aS + (size_t)N * 4;             // [N*4]
    float* dinv  = aD + (size_t)N * 4;             // [N]
    int* offs   = (int*)(dinv + N);                // [N]
    int* deg    = offs + N;                        // [N]
    int* bcur   = deg + N;                         // [NB+1]
    float* se   = (float*)(bcur + (NB + 1));       // [64]
    float* sf   = se + 64;                         // [64]
    unsigned short* Wt1 = (unsigned short*)(sf + 64);         // [144*128]
    unsigned short* Wt2 = Wt1 + 144 * 128;                    // [128*128]
    int2* pairs = (int2*)(Wt2 + 128 * 128);        // [(NB+1)*BCAP]
    int* csr    = (int*)(pairs + (size_t)(NB + 1) * BCAP);    // [NB*BCAP]

    // zero bcur + se + sf in one memset
    hipMemsetAsync(bcur, 0, (size_t)(NB + 1 + 128) * sizeof(int), stream);

    const int gemm_blocks = (N + 127) / 128;
    const int aggr_blocks = (N + 7) / 8;

    // L1: weight prep (16 blocks) || edge binning (NBA blocks)
    k_prep<<<NBA + WPB, 256, 0, stream>>>(Wgat, atts, attd, Wgcn, Wt1, Wt2,
                                          ei, bcur, pairs, E, NB);
    // L2: gemm0 || binB (padded CSR build) in one launch
    k_gemm_mfma<0><<<gemm_blocks + NB, 256, 0, stream>>>(
        x, Wt1, hb, N, nullptr, nullptr, nullptr, nullptr, aS, aD,
        pairs, bcur, csr, offs, deg, dinv, gemm_blocks);
    // L3..L6
    k_gat_aggr<<<aggr_blocks, 512, 0, stream>>>(hb, aS, aD, offs, deg, csr,
                                                raw1b, N);
    k_gemm_mfma<1><<<gemm_blocks, 256, 0, stream>>>(
        raw1b, Wt2, h2b, N, bgat, bn1w, bn1b, dinv, nullptr, nullptr,
        nullptr, nullptr, nullptr, nullptr, nullptr, nullptr, 1 << 30);
    k_gcn_aggr<<<aggr_blocks, 512, 0, stream>>>(h2b, offs, deg, csr, dinv,
                                                bgcn, bn2w, bn2b, wgate,
                                                bgate, wfc, batch, se, sf, N);
    k_fin<<<1, 64, 0, stream>>>(se, sf, bfc, out);
}

// Round 8
// 226.218 us; speedup vs baseline: 1.1463x; 1.1463x over previous
//
#include <hip/hip_runtime.h>
#include <math.h>

// GoBERT: GATConv(4x32) -> BN -> GCNConv(128) -> BN -> GlobalAttention -> FC
// Round 14: isolate. R13's pooling fusion regressed k_gcn_aggr 25->69us
// (4th proof the gather loop tolerates NO structural wrapping: if(act) +
// trailing barrier serialized the load batching; VALUBusy 49->31%).
//  - k_gcn_aggr + k_pool reverted to EXACT R10 code (early return, no
//    barrier, standalone pool with binary search).
//  - kept from R13: k_prep weight transpose split across 16 blocks (pure
//    work split of the 2-block ~20us straggler, no structure change).
// Everything else identical to R10 (229.6us config).

#define NEG_SLOPE 0.2f
#define BKT_BITS 7
#define BKT_SIZE 128
#define CHUNK_A 2048
#define BCAP 4096
#define WPB 16          // weight-prep blocks in k_prep

typedef __attribute__((ext_vector_type(8))) short short8v;
typedef __attribute__((ext_vector_type(4))) float floatx4;

__device__ __forceinline__ int lower_bound_i(const int* a, int n, int key) {
    int lo = 0, hi = n;
    while (lo < hi) {
        int mid = (lo + hi) >> 1;
        if (a[mid] < key) lo = mid + 1; else hi = mid;
    }
    return lo;
}

__device__ __forceinline__ unsigned pack_bf16(float lo, float hi) {
    unsigned ua = __float_as_uint(lo);
    unsigned ub = __float_as_uint(hi);
    ua = ua + 0x7fffu + ((ua >> 16) & 1u);
    ub = ub + 0x7fffu + ((ub >> 16) & 1u);
    return (ua >> 16) | (ub & 0xffff0000u);
}

__device__ __forceinline__ unsigned short bf16_1(float v) {
    unsigned u = __float_as_uint(v);
    u = u + 0x7fffu + ((u >> 16) & 1u);
    return (unsigned short)(u >> 16);
}

// ---------------- prep: weight transpose (blocks 0..15) || binA (rest) -----
// Wt1[144][128]: rows 0-127 = W_gat^T; 128-131 = W@att_src; 132-135 =
// W@att_dst; 136-143 = 0.  Wt2[128][128] = W_gcn^T.
// Blocks 0..7: Wt1 rows 18b..18b+18. Blocks 8..15: Wt2 rows 16(b-8)..+16.
__global__ __launch_bounds__(256) void k_prep(
    const float* __restrict__ W1, const float* __restrict__ atts,
    const float* __restrict__ attd, const float* __restrict__ W2,
    unsigned short* __restrict__ Wt1, unsigned short* __restrict__ Wt2,
    const int* __restrict__ ei, int* __restrict__ bcur,
    int2* __restrict__ pairs, int E, int NB)
{
    __shared__ float sW[128 * 129];          // 64.5KB; aliased by binA branch
    const int b = blockIdx.x;
    const int tid = threadIdx.x;
    if (b < WPB) {
        const bool first = b < 8;
        const float* W = first ? W1 : W2;
        unsigned short* Wt = first ? Wt1 : Wt2;
        for (int t = tid; t < 128 * 128; t += 256)
            sW[(t >> 7) * 129 + (t & 127)] = W[t];   // coalesced global read
        __syncthreads();
        const int j0 = first ? (b * 18) : ((b - 8) * 16);
        const int jn = first ? 18 : 16;
        for (int q = tid; q < jn * 128; q += 256) {
            int j = j0 + (q >> 7), i = q & 127;
            float v;
            if (j < 128) v = sW[i * 129 + j];        // lanes vary i: no conflict
            else if (j < 132) {
                int h = j - 128; float s = 0.f;
                for (int c = 0; c < 32; c++) s += sW[i * 129 + h * 32 + c] * atts[h * 32 + c];
                v = s;
            } else if (j < 136) {
                int h = j - 132; float s = 0.f;
                for (int c = 0; c < 32; c++) s += sW[i * 129 + h * 32 + c] * attd[h * 32 + c];
                v = s;
            } else v = 0.f;
            Wt[j * 128 + i] = bf16_1(v);
        }
    } else {
        int* h    = (int*)sW;                // [512]
        int* base = h + 512;                 // [512]
        for (int i = tid; i < NB + 1; i += 256) h[i] = 0;
        __syncthreads();
        const int c0 = (b - WPB) * CHUNK_A;
        int s[8], d[8], bk[8];
#pragma unroll
        for (int k = 0; k < 8; k++) {
            int e = c0 + k * 256 + tid;
            bool v = e < E;
            s[k] = v ? ei[e] : 0;
            d[k] = v ? ei[E + e] : 0;
            bk[k] = v ? (d[k] >> BKT_BITS) : NB;
            atomicAdd(&h[bk[k]], 1);
        }
        __syncthreads();
        for (int i = tid; i < NB + 1; i += 256) {
            int c = h[i];
            base[i] = c ? atomicAdd(&bcur[i], c) : 0;
            h[i] = 0;
        }
        __syncthreads();
#pragma unroll
        for (int k = 0; k < 8; k++) {
            int r = atomicAdd(&h[bk[k]], 1);
            pairs[(size_t)bk[k] * BCAP + base[bk[k]] + r] = make_int2(s[k], d[k]);
        }
    }
}

// ---------------- MFMA GEMM: 128 rows/block, Cb[N,64 pairs] ----------------
// MODE 0 launch also hosts binB in blocks >= gemmBlocks (independent work).
template<int MODE>
__global__ __launch_bounds__(256) void k_gemm_mfma(
    const void* __restrict__ Ain, const unsigned short* __restrict__ Wt,
    unsigned* __restrict__ Cb, int N,
    const float* __restrict__ pb, const float* __restrict__ pw,
    const float* __restrict__ pb2, const float* __restrict__ dinv,
    float* __restrict__ aS, float* __restrict__ aD,
    const int2* __restrict__ pairs, const int* __restrict__ bcnt,
    int* __restrict__ csr, int* __restrict__ offs, int* __restrict__ deg,
    float* __restrict__ dinvw, int gemmBlocks)
{
    constexpr int NCT = (MODE == 0) ? 9 : 8;
    __shared__ unsigned short sA[128 * 136];
    __shared__ unsigned short sB[NCT * 16 * 136];
    const int tid = threadIdx.x;

    if (MODE == 0 && (int)blockIdx.x >= gemmBlocks) {
        // ---------------- binB: bucket -> padded CSR ----------------
        __shared__ int wtot;
        int* hist  = (int*)sA;               // [128]
        int* start = hist + 128;             // [128]
        int* cur   = start + 128;            // [128]
        const int b = blockIdx.x - gemmBlocks;
        const int lane = tid & 63;
        const int d0 = b << BKT_BITS;
        const size_t pbg = (size_t)b * BCAP;
        const int cntb = bcnt[b];
        if (tid < BKT_SIZE) { hist[tid] = 0; cur[tid] = 0; }
        __syncthreads();
        for (int i = tid; i < cntb; i += 256)
            atomicAdd(&hist[pairs[pbg + i].y - d0], 1);
        __syncthreads();
        int own = (tid < BKT_SIZE) ? hist[tid] : 0;
        int incl = own;
#pragma unroll
        for (int st = 1; st < 64; st <<= 1) {
            int t = __shfl_up(incl, st);
            if (lane >= st) incl += t;
        }
        if (tid == 63) wtot = incl;          // wave-0 total
        __syncthreads();
        if (tid < BKT_SIZE) {
            if (tid >= 64) incl += wtot;
            int abs0 = (int)pbg + (incl - own);
            start[tid] = abs0;
            int dd = d0 + tid;
            if (dd < N) {
                offs[dd] = abs0;
                deg[dd] = own;
                dinvw[dd] = rsqrtf((float)(own + 1));
            }
        }
        __syncthreads();
        for (int i = tid; i < cntb; i += 256) {
            int2 p = pairs[pbg + i];
            int ld = p.y - d0;
            int r = atomicAdd(&cur[ld], 1);
            csr[start[ld] + r] = p.x;
        }
        return;
    }

    const int n0 = blockIdx.x * 128;

    // stage B (coalesced uint4, LDS row stride 136)
    {
        const uint4* Wg = (const uint4*)Wt;
        const int nq = NCT * 16 * 16;
        for (int q = tid; q < nq; q += 256) {
            uint4 v = Wg[q];
            int j = q >> 4, seg = q & 15;
            *(uint4*)(sB + j * 136 + seg * 8) = v;
        }
    }
    // stage A
    if (MODE == 0) {
        const float* A = (const float*)Ain;
        const int w4 = tid & 31;          // float4 within row
        const int r0 = tid >> 5;          // 0..7
#pragma unroll
        for (int i = 0; i < 16; i++) {
            int r = r0 + 8 * i;
            int gn = n0 + r;
            unsigned p0 = 0, p1 = 0;
            if (gn < N) {
                float4 v = *(const float4*)(A + (size_t)gn * 128 + w4 * 4);
                p0 = pack_bf16(v.x, v.y);
                p1 = pack_bf16(v.z, v.w);
            }
            *(uint2*)(sA + r * 136 + w4 * 4) = make_uint2(p0, p1);
        }
    } else {
        const unsigned short* A = (const unsigned short*)Ain;
        const int w8 = tid & 15;          // 8-channel group within row
        const int r0 = tid >> 4;          // 0..15
        const int k0 = w8 * 8;
        float pbv[8], pwv[8], p2v[8];
        *(float4*)(pbv)     = *(const float4*)(pb + k0);
        *(float4*)(pbv + 4) = *(const float4*)(pb + k0 + 4);
        *(float4*)(pwv)     = *(const float4*)(pw + k0);
        *(float4*)(pwv + 4) = *(const float4*)(pw + k0 + 4);
        *(float4*)(p2v)     = *(const float4*)(pb2 + k0);
        *(float4*)(p2v + 4) = *(const float4*)(pb2 + k0 + 4);
#pragma unroll
        for (int i = 0; i < 8; i++) {
            int r = r0 + 16 * i;
            int gn = n0 + r;
            uint4 outv = make_uint4(0, 0, 0, 0);
            if (gn < N) {
                uint4 v = *(const uint4*)(A + (size_t)gn * 128 + k0);
                unsigned uu[4] = {v.x, v.y, v.z, v.w};
                unsigned ro[4];
#pragma unroll
                for (int q2 = 0; q2 < 4; q2++) {
                    float lo = __uint_as_float(uu[q2] << 16);
                    float hi = __uint_as_float(uu[q2] & 0xffff0000u);
                    float t;
                    t = lo + pbv[2 * q2];     t = (t > 0.f) ? t : expm1f(t); lo = t * pwv[2 * q2]     + p2v[2 * q2];
                    t = hi + pbv[2 * q2 + 1]; t = (t > 0.f) ? t : expm1f(t); hi = t * pwv[2 * q2 + 1] + p2v[2 * q2 + 1];
                    ro[q2] = pack_bf16(lo, hi);
                }
                outv = make_uint4(ro[0], ro[1], ro[2], ro[3]);
            }
            *(uint4*)(sA + r * 136 + k0) = outv;
        }
    }
    __syncthreads();

    const int wid = tid >> 6, lane = tid & 63;
    const int quad = lane >> 4, l16 = lane & 15;

    floatx4 acc[2][NCT];
#pragma unroll
    for (int rt = 0; rt < 2; rt++)
#pragma unroll
        for (int ct = 0; ct < NCT; ct++) acc[rt][ct] = (floatx4){0.f, 0.f, 0.f, 0.f};

    const unsigned short* pa0 = sA + (wid * 32 + l16) * 136 + quad * 8;
    const unsigned short* pbt = sB + l16 * 136 + quad * 8;
#pragma unroll
    for (int ks = 0; ks < 4; ks++) {
        short8v a0 = *(const short8v*)(pa0 + ks * 32);
        short8v a1 = *(const short8v*)(pa0 + 16 * 136 + ks * 32);
#pragma unroll
        for (int ct = 0; ct < NCT; ct++) {
            short8v bv = *(const short8v*)(pbt + ct * (16 * 136) + ks * 32);
            acc[0][ct] = __builtin_amdgcn_mfma_f32_16x16x32_bf16(a0, bv, acc[0][ct], 0, 0, 0);
            acc[1][ct] = __builtin_amdgcn_mfma_f32_16x16x32_bf16(a1, bv, acc[1][ct], 0, 0, 0);
        }
    }

    // epilogue: lane = rows quad*4+r, col ct*16+l16
#pragma unroll
    for (int rt = 0; rt < 2; rt++) {
#pragma unroll
        for (int r = 0; r < 4; r++) {
            int n = n0 + wid * 32 + rt * 16 + quad * 4 + r;
            if (n >= N) continue;
            float s = MODE ? dinv[n] : 1.f;
#pragma unroll
            for (int ct = 0; ct < 4; ct++) {
                Cb[(size_t)n * 64 + ct * 16 + l16] =
                    pack_bf16(acc[rt][ct][r] * s, acc[rt][ct + 4][r] * s);
            }
            if (MODE == 0) {
                float e = acc[rt][8][r];
                if (l16 < 4) aS[(size_t)n * 4 + l16] = e;
                else if (l16 < 8) aD[(size_t)n * 4 + (l16 - 4)] = e;
            }
        }
    }
}

// ---------------- GAT aggregation: 8 nodes / 512-thread block --------------
// R10-proven structure: LDS-staged indices, readfirstlane SGPR bases,
// register triple-buffer (24 gathers in flight), lb(512,2). Pads: src=n, u=0.
__global__ __launch_bounds__(512, 2) void k_gat_aggr(
    const unsigned* __restrict__ hb, const float* __restrict__ aSg,
    const float* __restrict__ aDg, const int* __restrict__ offs,
    const int* __restrict__ deg, const int* __restrict__ csr,
    unsigned short* __restrict__ raw1b, int N)
{
    __shared__ __align__(16) float s_u[8][2][64][2];
    __shared__ __align__(16) int s_s[8][64];

    const int wid = threadIdx.x >> 6;
    const int lane = threadIdx.x & 63;
    const int n = blockIdx.x * 8 + wid;
    if (n >= N) return;

    const int beg = offs[n];
    const int cnt = deg[n] + 1;                     // + self loop
    const float4 ad = *(const float4*)(aDg + (size_t)n * 4);
    const int hA = lane >> 5;
    const float* pu = &s_u[wid][hA][0][0];
    const int* ps = &s_s[wid][0];
    const unsigned* hbl = hb + lane;

    float t0 = 0.f, t1 = 0.f, t2 = 0.f, t3 = 0.f;
    float accLo = 0.f, accHi = 0.f;

    auto issue8 = [&](int j, unsigned (&v)[8]) {
        int4 A = *(const int4*)&ps[j];
        int4 B = *(const int4*)&ps[j + 4];
        int s0 = __builtin_amdgcn_readfirstlane(A.x);
        int s1 = __builtin_amdgcn_readfirstlane(A.y);
        int s2 = __builtin_amdgcn_readfirstlane(A.z);
        int s3 = __builtin_amdgcn_readfirstlane(A.w);
        int s4 = __builtin_amdgcn_readfirstlane(B.x);
        int s5 = __builtin_amdgcn_readfirstlane(B.y);
        int s6 = __builtin_amdgcn_readfirstlane(B.z);
        int s7 = __builtin_amdgcn_readfirstlane(B.w);
        v[0] = hbl[(size_t)s0 << 6];
        v[1] = hbl[(size_t)s1 << 6];
        v[2] = hbl[(size_t)s2 << 6];
        v[3] = hbl[(size_t)s3 << 6];
        v[4] = hbl[(size_t)s4 << 6];
        v[5] = hbl[(size_t)s5 << 6];
        v[6] = hbl[(size_t)s6 << 6];
        v[7] = hbl[(size_t)s7 << 6];
    };
    auto consume8 = [&](int j, unsigned (&v)[8]) {
        float4 u01 = *(const float4*)&pu[2 * j];
        float4 u23 = *(const float4*)&pu[2 * j + 4];
        float4 u45 = *(const float4*)&pu[2 * j + 8];
        float4 u67 = *(const float4*)&pu[2 * j + 12];
        float uw[16] = {u01.x, u01.y, u01.z, u01.w,
                        u23.x, u23.y, u23.z, u23.w,
                        u45.x, u45.y, u45.z, u45.w,
                        u67.x, u67.y, u67.z, u67.w};
#pragma unroll
        for (int k = 0; k < 8; k++) {
            float lo = __uint_as_float(v[k] << 16);
            float hi = __uint_as_float(v[k] & 0xffff0000u);
            accLo += uw[2 * k] * lo;
            accHi += uw[2 * k + 1] * hi;
        }
    };

    for (int base = 0; base < cnt; base += 64) {
        int idx = base + lane;
        bool valid = idx < cnt;
        int src = n;
        if (valid && idx > 0) src = csr[beg + idx - 1];
        float u0 = 0.f, u1 = 0.f, u2 = 0.f, u3 = 0.f;
        if (valid) {
            float4 as = *(const float4*)(aSg + (size_t)src * 4);
            float l0 = as.x + ad.x; l0 = (l0 > 0.f) ? l0 : NEG_SLOPE * l0;
            float l1 = as.y + ad.y; l1 = (l1 > 0.f) ? l1 : NEG_SLOPE * l1;
            float l2 = as.z + ad.z; l2 = (l2 > 0.f) ? l2 : NEG_SLOPE * l2;
            float l3 = as.w + ad.w; l3 = (l3 > 0.f) ? l3 : NEG_SLOPE * l3;
            u0 = __expf(l0); u1 = __expf(l1); u2 = __expf(l2); u3 = __expf(l3);
        }
        t0 += u0; t1 += u1; t2 += u2; t3 += u3;
        s_s[wid][lane] = src;
        *(float2*)&s_u[wid][0][lane][0] = make_float2(u0, u2);
        *(float2*)&s_u[wid][1][lane][0] = make_float2(u1, u3);

        int cc = min(64, cnt - base);
        int ccp = (cc + 7) & ~7;                    // pads contribute u=0
        int ng = ccp >> 3;
        unsigned v0[8], v1[8], v2[8];
        if (ng > 0) issue8(0, v0);
        if (ng > 1) issue8(8, v1);
        if (ng > 2) issue8(16, v2);
        if (ng > 0) consume8(0, v0);
        if (ng > 1) consume8(8, v1);
        if (ng > 2) consume8(16, v2);
        for (int j = 24; j < ccp; j += 8) {         // rare (deg > 23)
            issue8(j, v0);
            consume8(j, v0);
        }
    }
#pragma unroll
    for (int msk = 1; msk < 64; msk <<= 1) {
        t0 += __shfl_xor(t0, msk);
        t1 += __shfl_xor(t1, msk);
        t2 += __shfl_xor(t2, msk);
        t3 += __shfl_xor(t3, msk);
    }
    float sLo = (hA ? t1 : t0) + 1e-16f;
    float sHi = (hA ? t3 : t2) + 1e-16f;
    raw1b[(size_t)n * 128 + lane]      = bf16_1(accLo / sLo);
    raw1b[(size_t)n * 128 + 64 + lane] = bf16_1(accHi / sHi);
}

// ---------------- GCN aggregation + fused BN2/ELU/gate/fc ------------------
// EXACT R10 structure (early return, no barrier, standalone epilogue).
__global__ __launch_bounds__(512, 2) void k_gcn_aggr(
    const unsigned* __restrict__ h2b, const int* __restrict__ offs,
    const int* __restrict__ deg, const int* __restrict__ csr,
    const float* __restrict__ dinv, const float* __restrict__ bgcn,
    const float* __restrict__ bn2w, const float* __restrict__ bn2b,
    const float* __restrict__ wgate, const float* __restrict__ bgate,
    const float* __restrict__ wfc,
    float* __restrict__ gate, float* __restrict__ fcdot, int N)
{
    __shared__ __align__(16) int s_s[8][64];
    __shared__ __align__(16) float s_w[8][64];

    const int wid = threadIdx.x >> 6;
    const int lane = threadIdx.x & 63;
    const int n = blockIdx.x * 8 + wid;
    if (n >= N) return;

    const int beg = offs[n];
    const int cnt = deg[n] + 1;
    const float dn = dinv[n];
    const int* ps = &s_s[wid][0];
    const float* pw = &s_w[wid][0];
    const unsigned* h2l = h2b + lane;

    float accLo = 0.f, accHi = 0.f;

    auto issue8 = [&](int j, unsigned (&v)[8]) {
        int4 A = *(const int4*)&ps[j];
        int4 B = *(const int4*)&ps[j + 4];
        int s0 = __builtin_amdgcn_readfirstlane(A.x);
        int s1 = __builtin_amdgcn_readfirstlane(A.y);
        int s2 = __builtin_amdgcn_readfirstlane(A.z);
        int s3 = __builtin_amdgcn_readfirstlane(A.w);
        int s4 = __builtin_amdgcn_readfirstlane(B.x);
        int s5 = __builtin_amdgcn_readfirstlane(B.y);
        int s6 = __builtin_amdgcn_readfirstlane(B.z);
        int s7 = __builtin_amdgcn_readfirstlane(B.w);
        v[0] = h2l[(size_t)s0 << 6];
        v[1] = h2l[(size_t)s1 << 6];
        v[2] = h2l[(size_t)s2 << 6];
        v[3] = h2l[(size_t)s3 << 6];
        v[4] = h2l[(size_t)s4 << 6];
        v[5] = h2l[(size_t)s5 << 6];
        v[6] = h2l[(size_t)s6 << 6];
        v[7] = h2l[(size_t)s7 << 6];
    };
    auto consume8 = [&](int j, unsigned (&v)[8]) {
        float4 wA = *(const float4*)&pw[j];
        float4 wB = *(const float4*)&pw[j + 4];
        float w8[8] = {wA.x, wA.y, wA.z, wA.w, wB.x, wB.y, wB.z, wB.w};
#pragma unroll
        for (int k = 0; k < 8; k++) {
            float lo = __uint_as_float(v[k] << 16);
            float hi = __uint_as_float(v[k] & 0xffff0000u);
            accLo += w8[k] * lo;
            accHi += w8[k] * hi;
        }
    };

    for (int base = 0; base < cnt; base += 64) {
        int idx = base + lane;
        bool valid = idx < cnt;
        int src = n;
        if (valid && idx > 0) src = csr[beg + idx - 1];
        s_s[wid][lane] = src;
        s_w[wid][lane] = valid ? 1.f : 0.f;

        int cc = min(64, cnt - base);
        int ccp = (cc + 7) & ~7;                    // pads carry w=0
        int ng = ccp >> 3;
        unsigned v0[8], v1[8], v2[8];
        if (ng > 0) issue8(0, v0);
        if (ng > 1) issue8(8, v1);
        if (ng > 2) issue8(16, v2);
        if (ng > 0) consume8(0, v0);
        if (ng > 1) consume8(8, v1);
        if (ng > 2) consume8(16, v2);
        for (int j = 24; j < ccp; j += 8) {
            issue8(j, v0);
            consume8(j, v0);
        }
    }
    float v0f = dn * accLo + bgcn[lane];
    v0f = (v0f > 0.f) ? v0f : expm1f(v0f);
    v0f = v0f * bn2w[lane] + bn2b[lane];
    float v1f = dn * accHi + bgcn[lane + 64];
    v1f = (v1f > 0.f) ? v1f : expm1f(v1f);
    v1f = v1f * bn2w[lane + 64] + bn2b[lane + 64];

    float g = v0f * wgate[lane] + v1f * wgate[lane + 64];
    float f = v0f * wfc[lane]   + v1f * wfc[lane + 64];
#pragma unroll
    for (int msk = 1; msk < 64; msk <<= 1) {
        g += __shfl_xor(g, msk);
        f += __shfl_xor(f, msk);
    }
    if (lane == 0) { gate[n] = g + bgate[0]; fcdot[n] = f; }
}

// ---------------- pooling softmax over scalars: one block / graph ----------
__global__ __launch_bounds__(256) void k_pool(
    const float* __restrict__ gate, const float* __restrict__ fcdot,
    const int* __restrict__ batch, const float* __restrict__ bfc,
    float* __restrict__ out, int N)
{
    __shared__ float red[256];
    __shared__ int range[2];
    const int g = blockIdx.x;
    const int tid = threadIdx.x;
    if (tid < 2) range[tid] = lower_bound_i(batch, N, g + tid);
    __syncthreads();
    const int lo = range[0], hi = range[1];
    float se = 0.f, sf = 0.f;
    for (int i = lo + tid; i < hi; i += 256) {
        float e = __expf(gate[i]);
        se += e;
        sf += e * fcdot[i];
    }
    red[tid] = se; __syncthreads();
    for (int s = 128; s > 0; s >>= 1) {
        if (tid < s) red[tid] += red[tid + s];
        __syncthreads();
    }
    se = red[0]; __syncthreads();
    red[tid] = sf; __syncthreads();
    for (int s = 128; s > 0; s >>= 1) {
        if (tid < s) red[tid] += red[tid + s];
        __syncthreads();
    }
    sf = red[0];
    if (tid == 0) out[g] = sf / (se + 1e-16f) + bfc[0];
}

// ---------------------------------------------------------------------------
extern "C" void kernel_launch(void* const* d_in, const int* in_sizes, int n_in,
                              void* d_out, int out_size, void* d_ws, size_t ws_size,
                              hipStream_t stream) {
    const float* x     = (const float*)d_in[0];
    const int*   ei    = (const int*)d_in[1];
    const int*   batch = (const int*)d_in[2];
    const float* Wgat  = (const float*)d_in[3];
    const float* atts  = (const float*)d_in[4];
    const float* attd  = (const float*)d_in[5];
    const float* bgat  = (const float*)d_in[6];
    const float* bn1w  = (const float*)d_in[7];
    const float* bn1b  = (const float*)d_in[8];
    const float* Wgcn  = (const float*)d_in[9];
    const float* bgcn  = (const float*)d_in[10];
    const float* bn2w  = (const float*)d_in[11];
    const float* bn2b  = (const float*)d_in[12];
    const float* wgate = (const float*)d_in[13];
    const float* bgate = (const float*)d_in[14];
    const float* wfc   = (const float*)d_in[15];
    const float* bfc   = (const float*)d_in[16];
    float* out = (float*)d_out;

    const int N = in_sizes[0] / 128;
    const int E = in_sizes[1] / 2;
    const int NB = (N + BKT_SIZE - 1) / BKT_SIZE;
    const int NBA = (E + CHUNK_A - 1) / CHUNK_A;   // binA blocks

    unsigned* hb  = (unsigned*)d_ws;               // bf16 h table   [N*64]
    unsigned* h2b = hb + (size_t)N * 64;           // bf16 h2s table [N*64]
    unsigned short* raw1b = (unsigned short*)(h2b + (size_t)N * 64); // [N*128]
    float* aS    = (float*)(raw1b + (size_t)N * 128); // [N*4]
    float* aD    = aS + (size_t)N * 4;             // [N*4]
    float* gate  = aD + (size_t)N * 4;             // [N]
    float* fcdot = gate + N;                       // [N]
    float* dinv  = fcdot + N;                      // [N]
    int* offs   = (int*)(dinv + N);                // [N]
    int* deg    = offs + N;                        // [N]
    int* bcur   = deg + N;                         // [NB+1]
    unsigned short* Wt1 = (unsigned short*)(bcur + (NB + 1)); // [144*128]
    unsigned short* Wt2 = Wt1 + 144 * 128;                    // [128*128]
    int2* pairs = (int2*)(Wt2 + 128 * 128);        // [(NB+1)*BCAP]
    int* csr    = (int*)(pairs + (size_t)(NB + 1) * BCAP);    // [NB*BCAP]

    hipMemsetAsync(bcur, 0, (size_t)(NB + 1) * sizeof(int), stream);

    const int gemm_blocks = (N + 127) / 128;
    const int aggr_blocks = (N + 7) / 8;

    // L1: weight prep (16 blocks) || edge binning (NBA blocks)
    k_prep<<<NBA + WPB, 256, 0, stream>>>(Wgat, atts, attd, Wgcn, Wt1, Wt2,
                                          ei, bcur, pairs, E, NB);
    // L2: gemm0 || binB (padded CSR build) in one launch
    k_gemm_mfma<0><<<gemm_blocks + NB, 256, 0, stream>>>(
        x, Wt1, hb, N, nullptr, nullptr, nullptr, nullptr, aS, aD,
        pairs, bcur, csr, offs, deg, dinv, gemm_blocks);
    // L3..L6
    k_gat_aggr<<<aggr_blocks, 512, 0, stream>>>(hb, aS, aD, offs, deg, csr,
                                                raw1b, N);
    k_gemm_mfma<1><<<gemm_blocks, 256, 0, stream>>>(
        raw1b, Wt2, h2b, N, bgat, bn1w, bn1b, dinv, nullptr, nullptr,
        nullptr, nullptr, nullptr, nullptr, nullptr, nullptr, 1 << 30);
    k_gcn_aggr<<<aggr_blocks, 512, 0, stream>>>(h2b, offs, deg, csr, dinv,
                                                bgcn, bn2w, bn2b, wgate,
                                                bgate, wfc, gate, fcdot, N);
    k_pool<<<64, 256, 0, stream>>>(gate, fcdot, batch, bfc, out, N);
}